// Round 16
// baseline (248.059 us; speedup 1.0000x reference)
//
#include <hip/hip_runtime.h>
#include <hip/hip_bf16.h>

#define N_NODES 50000
#define N_EDGES 800000

constexpr int NP = 50176;                          // N_NODES padded to 256
constexpr int NXCD = 8;
constexpr int NR = NP / NXCD;                      // 6272 nodes per XCD range
constexpr int FSTR = 391;                          // stripes of 2048 edges
constexpr int ES = 2048;                           // 391*2048 = 800768 >= E
constexpr int ATB = NXCD * FSTR;                   // 3128 count/fill blocks (b&7 = XCD)
constexpr int PGB = 98 * 32;                       // 3136 pregemm blocks (XCD-swizzled)
constexpr int WCB2 = (64 * 256 + 128 * 128) / 256; // 128 blocks for Wc2+Wc3

typedef __attribute__((ext_vector_type(8))) short bf16x8;
typedef __attribute__((ext_vector_type(4))) float f32x4;

__device__ __forceinline__ unsigned short f2bf(float f) {
    unsigned u = __float_as_uint(f);
    u += 0x7FFFu + ((u >> 16) & 1u);   // round-nearest-even
    return (unsigned short)(u >> 16);
}

__device__ __forceinline__ bf16x8 pack8(float4 f0, float4 f1) {
    bf16x8 r;
    r[0] = (short)f2bf(f0.x); r[1] = (short)f2bf(f0.y);
    r[2] = (short)f2bf(f0.z); r[3] = (short)f2bf(f0.w);
    r[4] = (short)f2bf(f1.x); r[5] = (short)f2bf(f1.y);
    r[6] = (short)f2bf(f1.z); r[7] = (short)f2bf(f1.w);
    return r;
}

// ---------------- zero counters ----------------
__global__ void zero_kernel(int* __restrict__ p, int n) {
    int i = blockIdx.x * 256 + threadIdx.x;
    if (i < n) p[i] = 0;
}

// ---------------- prep: XCD-local count (high TLP) + pregemm + Wc builds ----------------
// R15 post-mortem: XCD-local non-returning count beat the 41us returning wall
// (~32us), but fill starved at 392 blocks (R11 lesson re-learned). R16: same
// partition with 2048-edge stripes -> 3128 blocks for BOTH count and fill.
__global__ __launch_bounds__(256, 8) void prep_kernel(
        const int* __restrict__ dst, int* __restrict__ cnt,
        const float* __restrict__ x,
        const float* __restrict__ W1l, const float* __restrict__ b1,
        const float* __restrict__ W1r,
        const float* __restrict__ W2l, const float* __restrict__ W2r,
        const float* __restrict__ W3l, const float* __restrict__ W3r,
        unsigned short* __restrict__ xlb, unsigned short* __restrict__ s1b,
        unsigned short* __restrict__ Wc2, unsigned short* __restrict__ Wc3) {
    __shared__ unsigned short Asl[64 * 136];   // 64 rows, 272B stride
    int b = blockIdx.x;
    int tid = threadIdx.x;
    if (b < ATB) {
        // ---- XCD-local count: non-returning atomics on this XCD's node range ----
        int xcd = b & 7, st = b >> 3;
        int lo = xcd * NR;
        int e0 = st * ES;
        int ne = N_EDGES - e0; if (ne > ES) ne = ES;
        if (ne > 0) {
            int ne4 = ne >> 2;
            const int4* dp = reinterpret_cast<const int4*>(dst + e0);
            for (int j = tid; j < ne4; j += 256) {   // <= 2 iterations
                int4 d4 = dp[j];
                if ((unsigned)(d4.x - lo) < (unsigned)NR) atomicAdd(&cnt[d4.x], 1);
                if ((unsigned)(d4.y - lo) < (unsigned)NR) atomicAdd(&cnt[d4.y], 1);
                if ((unsigned)(d4.z - lo) < (unsigned)NR) atomicAdd(&cnt[d4.z], 1);
                if ((unsigned)(d4.w - lo) < (unsigned)NR) atomicAdd(&cnt[d4.w], 1);
            }
        }
    } else if (b < ATB + PGB) {
        // ---- layer-1 pregemm, XCD-local mapping (R14) ----
        int p = b - ATB;
        int ng = (p >> 5) * 8 + (p & 7);
        int cg = (p >> 3) & 3;
        if (ng >= 782) return;
        int nb0 = ng * 64;
        {
            int r = tid >> 2, q = tid & 3;
            int node = nb0 + r;
            int ncl = node < N_NODES ? node : 0;
            const float4* xp = reinterpret_cast<const float4*>(x + (size_t)ncl * 128 + q * 32);
            #pragma unroll
            for (int i = 0; i < 4; ++i) {
                float4 f0 = xp[2 * i];
                float4 f1 = xp[2 * i + 1];
                uint4 w;
                w.x = (unsigned)f2bf(f0.x) | ((unsigned)f2bf(f0.y) << 16);
                w.y = (unsigned)f2bf(f0.z) | ((unsigned)f2bf(f0.w) << 16);
                w.z = (unsigned)f2bf(f1.x) | ((unsigned)f2bf(f1.y) << 16);
                w.w = (unsigned)f2bf(f1.z) | ((unsigned)f2bf(f1.w) << 16);
                *reinterpret_cast<uint4*>(&Asl[r * 136 + q * 32 + i * 8]) = w;
            }
        }
        __syncthreads();
        int wave = tid >> 6, lane = tid & 63;
        int arow = lane & 15, kseg = lane >> 4;
        int col = cg * 64 + wave * 16 + arow;      // 0..255
        const float* wrow = (col < 128) ? (W1l + (size_t)col * 128)
                                        : (W1r + (size_t)(col - 128) * 128);
        bf16x8 bw[4];
        #pragma unroll
        for (int kk = 0; kk < 4; ++kk) {
            float4 f0 = *reinterpret_cast<const float4*>(wrow + kk * 32 + kseg * 8);
            float4 f1 = *reinterpret_cast<const float4*>(wrow + kk * 32 + kseg * 8 + 4);
            bw[kk] = pack8(f0, f1);
        }
        float bias_v = (col < 128) ? 0.f : b1[col - 128];
        unsigned short* outbase = (col < 128) ? xlb : s1b;
        int ocol = (col < 128) ? col : (col - 128);
        #pragma unroll
        for (int g = 0; g < 4; ++g) {
            bf16x8 a[4];
            #pragma unroll
            for (int kk = 0; kk < 4; ++kk)
                a[kk] = *reinterpret_cast<const bf16x8*>(
                    &Asl[(g * 16 + arow) * 136 + kk * 32 + kseg * 8]);
            f32x4 acc = {0.f, 0.f, 0.f, 0.f};
            #pragma unroll
            for (int kk = 0; kk < 4; ++kk)
                acc = __builtin_amdgcn_mfma_f32_16x16x32_bf16(a[kk], bw[kk], acc, 0, 0, 0);
            int gn0 = nb0 + g * 16 + kseg * 4;
            #pragma unroll
            for (int r = 0; r < 4; ++r) {
                int gn = gn0 + r;
                if (gn < N_NODES)
                    outbase[(size_t)gn * 128 + ocol] = f2bf(acc[r] + bias_v);
            }
        }
    } else {
        // ---- Wc2 / Wc3 builds ----
        int idx = (b - ATB - PGB) * 256 + tid;   // [0, 32768)
        if (idx < 16384) {
            int nr = idx >> 8, k = idx & 255;
            float v = (k < 128) ? W2l[nr * 128 + k] : W2r[nr * 128 + (k - 128)];
            Wc2[idx] = f2bf(v);
        } else {
            int j = idx - 16384;
            int nr = j >> 7, k = j & 127;
            float v = (k < 64) ? W3l[nr * 64 + k] : W3r[nr * 64 + (k - 64)];
            Wc3[j] = f2bf(v);
        }
    }
}

// scan -> row_ptr, inv_deg, cursor init
__global__ void assign_kernel(const int* __restrict__ cnt, int* __restrict__ row_ptr,
                              int* __restrict__ cursor,
                              float* __restrict__ inv_deg, int* __restrict__ total, int n) {
    int i = blockIdx.x * blockDim.x + threadIdx.x;
    int lane = threadIdx.x & 63;
    int v = (i < n) ? cnt[i] : 0;
    int s = v;
    #pragma unroll
    for (int off = 1; off < 64; off <<= 1) {
        int t = __shfl_up(s, off);
        if (lane >= off) s += t;
    }
    int base = 0;
    if (lane == 63) base = atomicAdd(total, s);
    base = __shfl(base, 63);
    if (i < n) {
        int rp = base + s - v;
        row_ptr[i] = rp;
        cursor[i] = rp;
        inv_deg[i] = 1.0f / (float)(v > 1 ? v : 1);
    }
}

// ---------------- fill: XCD-local cursor-atomic scatter, high TLP ----------------
__global__ __launch_bounds__(256) void fill_kernel(
        const int* __restrict__ src, const int* __restrict__ dst,
        int* __restrict__ cursor, int* __restrict__ edge_src) {
    int b = blockIdx.x;
    int tid = threadIdx.x;
    int xcd = b & 7, st = b >> 3;
    int lo = xcd * NR;
    int e0 = st * ES;
    int ne = N_EDGES - e0; if (ne > ES) ne = ES;
    if (ne <= 0) return;
    int ne4 = ne >> 2;
    const int4* dp = reinterpret_cast<const int4*>(dst + e0);
    const int4* sp = reinterpret_cast<const int4*>(src + e0);
    for (int j = tid; j < ne4; j += 256) {   // <= 2 iterations
        int4 d4 = dp[j];
        int4 s4 = sp[j];
        if ((unsigned)(d4.x - lo) < (unsigned)NR) {
            int p = atomicAdd(&cursor[d4.x], 1);
            edge_src[p] = s4.x;
        }
        if ((unsigned)(d4.y - lo) < (unsigned)NR) {
            int p = atomicAdd(&cursor[d4.y], 1);
            edge_src[p] = s4.y;
        }
        if ((unsigned)(d4.z - lo) < (unsigned)NR) {
            int p = atomicAdd(&cursor[d4.z], 1);
            edge_src[p] = s4.z;
        }
        if ((unsigned)(d4.w - lo) < (unsigned)NR) {
            int p = atomicAdd(&cursor[d4.w], 1);
            edge_src[p] = s4.w;
        }
    }
}

// ---------------- layer-1: aggregate xlb + merge s1b (relu) ----------------
__global__ __launch_bounds__(256) void agg1_kernel(
        const unsigned short* __restrict__ hb,     // xlb
        const int* __restrict__ row_ptr, const int* __restrict__ cnt,
        const int* __restrict__ edge_src, const float* __restrict__ inv_deg,
        const unsigned short* __restrict__ s1b,
        float* __restrict__ outF, unsigned short* __restrict__ h1b, int n) {
    constexpr int LPR = 16, EPW = 4;
    int wid = (blockIdx.x * 256 + threadIdx.x) >> 6;
    int lane = threadIdx.x & 63;
    if (wid >= n) return;
    int beg = row_ptr[wid];
    int end = beg + cnt[wid];
    float inv = inv_deg[wid];
    int sub = lane / LPR, li = lane % LPR;

    float acc[8];
    #pragma unroll
    for (int j = 0; j < 8; ++j) acc[j] = 0.f;
    for (int e0 = beg; e0 < end; e0 += 4 * EPW) {
        int ea = e0 + sub, eb = ea + EPW, ec = ea + 2 * EPW, ed = ea + 3 * EPW;
        uint4 v0 = {0u,0u,0u,0u}, v1 = {0u,0u,0u,0u}, v2 = {0u,0u,0u,0u}, v3 = {0u,0u,0u,0u};
        if (ea < end) v0 = *reinterpret_cast<const uint4*>(hb + (size_t)edge_src[ea] * 128 + li * 8);
        if (eb < end) v1 = *reinterpret_cast<const uint4*>(hb + (size_t)edge_src[eb] * 128 + li * 8);
        if (ec < end) v2 = *reinterpret_cast<const uint4*>(hb + (size_t)edge_src[ec] * 128 + li * 8);
        if (ed < end) v3 = *reinterpret_cast<const uint4*>(hb + (size_t)edge_src[ed] * 128 + li * 8);
        unsigned w;
        #define ACCW(u, j0) w = (u); acc[j0] += __uint_as_float(w << 16); acc[j0+1] += __uint_as_float(w & 0xFFFF0000u)
        ACCW(v0.x, 0); ACCW(v0.y, 2); ACCW(v0.z, 4); ACCW(v0.w, 6);
        ACCW(v1.x, 0); ACCW(v1.y, 2); ACCW(v1.z, 4); ACCW(v1.w, 6);
        ACCW(v2.x, 0); ACCW(v2.y, 2); ACCW(v2.z, 4); ACCW(v2.w, 6);
        ACCW(v3.x, 0); ACCW(v3.y, 2); ACCW(v3.z, 4); ACCW(v3.w, 6);
        #undef ACCW
    }
    #pragma unroll
    for (int off = LPR; off < 64; off <<= 1) {
        #pragma unroll
        for (int j = 0; j < 8; ++j) acc[j] += __shfl_xor(acc[j], off);
    }
    if (lane < LPR) {
        uint4 s4 = *reinterpret_cast<const uint4*>(s1b + (size_t)wid * 128 + li * 8);
        float v[8];
        v[0] = fmaxf(acc[0] * inv + __uint_as_float(s4.x << 16), 0.f);
        v[1] = fmaxf(acc[1] * inv + __uint_as_float(s4.x & 0xFFFF0000u), 0.f);
        v[2] = fmaxf(acc[2] * inv + __uint_as_float(s4.y << 16), 0.f);
        v[3] = fmaxf(acc[3] * inv + __uint_as_float(s4.y & 0xFFFF0000u), 0.f);
        v[4] = fmaxf(acc[4] * inv + __uint_as_float(s4.z << 16), 0.f);
        v[5] = fmaxf(acc[5] * inv + __uint_as_float(s4.z & 0xFFFF0000u), 0.f);
        v[6] = fmaxf(acc[6] * inv + __uint_as_float(s4.w << 16), 0.f);
        v[7] = fmaxf(acc[7] * inv + __uint_as_float(s4.w & 0xFFFF0000u), 0.f);
        float4 r0 = {v[0], v[1], v[2], v[3]};
        float4 r1 = {v[4], v[5], v[6], v[7]};
        float* op = outF + (size_t)wid * 320 + li * 8;
        *reinterpret_cast<float4*>(op) = r0;
        *reinterpret_cast<float4*>(op + 4) = r1;
        uint4 w;
        w.x = (unsigned)f2bf(v[0]) | ((unsigned)f2bf(v[1]) << 16);
        w.y = (unsigned)f2bf(v[2]) | ((unsigned)f2bf(v[3]) << 16);
        w.z = (unsigned)f2bf(v[4]) | ((unsigned)f2bf(v[5]) << 16);
        w.w = (unsigned)f2bf(v[6]) | ((unsigned)f2bf(v[7]) << 16);
        *reinterpret_cast<uint4*>(h1b + (size_t)wid * 128 + li * 8) = w;
    }
}

// ---------------- mean aggregation (layers 2,3): wave per node, ILP-4 ----------------
template<int D>
__global__ __launch_bounds__(256) void agg_kernel(
        const unsigned short* __restrict__ hb,
        const int* __restrict__ row_ptr, const int* __restrict__ cnt,
        const int* __restrict__ edge_src,
        const float* __restrict__ inv_deg, unsigned short* __restrict__ meanb, int n) {
    constexpr int LPR = D / 8;
    constexpr int EPW = 64 / LPR;
    int wid = (blockIdx.x * 256 + threadIdx.x) >> 6;
    int lane = threadIdx.x & 63;
    if (wid >= n) return;
    int beg = row_ptr[wid];
    int end = beg + cnt[wid];
    float inv = inv_deg[wid];
    int sub = lane / LPR;
    int li = lane % LPR;

    float acc[8];
    #pragma unroll
    for (int j = 0; j < 8; ++j) acc[j] = 0.f;

    for (int e0 = beg; e0 < end; e0 += 4 * EPW) {
        int ea = e0 + sub;
        int eb = ea + EPW;
        int ec = ea + 2 * EPW;
        int ed = ea + 3 * EPW;
        uint4 v0 = {0u,0u,0u,0u}, v1 = {0u,0u,0u,0u}, v2 = {0u,0u,0u,0u}, v3 = {0u,0u,0u,0u};
        if (ea < end) v0 = *reinterpret_cast<const uint4*>(hb + (size_t)edge_src[ea] * D + li * 8);
        if (eb < end) v1 = *reinterpret_cast<const uint4*>(hb + (size_t)edge_src[eb] * D + li * 8);
        if (ec < end) v2 = *reinterpret_cast<const uint4*>(hb + (size_t)edge_src[ec] * D + li * 8);
        if (ed < end) v3 = *reinterpret_cast<const uint4*>(hb + (size_t)edge_src[ed] * D + li * 8);
        unsigned w;
        #define ACCW(u, j0) w = (u); acc[j0] += __uint_as_float(w << 16); acc[j0+1] += __uint_as_float(w & 0xFFFF0000u)
        ACCW(v0.x, 0); ACCW(v0.y, 2); ACCW(v0.z, 4); ACCW(v0.w, 6);
        ACCW(v1.x, 0); ACCW(v1.y, 2); ACCW(v1.z, 4); ACCW(v1.w, 6);
        ACCW(v2.x, 0); ACCW(v2.y, 2); ACCW(v2.z, 4); ACCW(v2.w, 6);
        ACCW(v3.x, 0); ACCW(v3.y, 2); ACCW(v3.z, 4); ACCW(v3.w, 6);
        #undef ACCW
    }
    #pragma unroll
    for (int off = LPR; off < 64; off <<= 1) {
        #pragma unroll
        for (int j = 0; j < 8; ++j) acc[j] += __shfl_xor(acc[j], off);
    }
    if (lane < LPR) {
        uint4 w;
        w.x = (unsigned)f2bf(acc[0] * inv) | ((unsigned)f2bf(acc[1] * inv) << 16);
        w.y = (unsigned)f2bf(acc[2] * inv) | ((unsigned)f2bf(acc[3] * inv) << 16);
        w.z = (unsigned)f2bf(acc[4] * inv) | ((unsigned)f2bf(acc[5] * inv) << 16);
        w.w = (unsigned)f2bf(acc[6] * inv) | ((unsigned)f2bf(acc[7] * inv) << 16);
        *reinterpret_cast<uint4*>(meanb + (size_t)wid * D + li * 8) = w;
    }
}

// ---------------- MFMA GEMM v3 (R8 exact): B-in-registers, M-loop per wave ----------------
template<int K, int DOUT, bool WB>
__global__ __launch_bounds__(256, 3) void mfma_gemm_kernel(
        const unsigned short* __restrict__ Ab,
        const unsigned short* __restrict__ Fb,
        const unsigned short* __restrict__ Wc,
        const float* __restrict__ bias,
        float* __restrict__ out, int outs,
        unsigned short* __restrict__ outb, int n) {
    constexpr int DIN = K / 2;
    constexpr int KK = K / 32;
    constexpr int NWC = DOUT / 32;
    constexpr int NWM = 4 / NWC;
    constexpr int GW = 4;
    constexpr int BM = 16 * GW * NWM;
    int wave = threadIdx.x >> 6;
    int lane = threadIdx.x & 63;
    int wc = wave % NWC;
    int wm = wave / NWC;
    int arow = lane & 15;
    int kseg = lane >> 4;

    bf16x8 b0[KK], b1[KK];
    {
        const unsigned short* wp0 = Wc + (size_t)(wc * 32 + arow) * K + kseg * 8;
        const unsigned short* wp1 = wp0 + (size_t)16 * K;
        #pragma unroll
        for (int kk = 0; kk < KK; ++kk) {
            b0[kk] = *reinterpret_cast<const bf16x8*>(wp0 + kk * 32);
            b1[kk] = *reinterpret_cast<const bf16x8*>(wp1 + kk * 32);
        }
    }
    float bv0 = bias[wc * 32 + arow];
    float bv1 = bias[wc * 32 + 16 + arow];

    int g0 = blockIdx.x * (BM / 16) + wm * GW;

    bf16x8 a0[KK], a1[KK];

    #define LOADA(g, dst)                                                          \
    {                                                                              \
        int node = (g0 + (g)) * 16 + arow;                                         \
        int ncl = node < n ? node : 0;                                             \
        _Pragma("unroll")                                                          \
        for (int kk = 0; kk < KK; ++kk) {                                          \
            int k = kk * 32 + kseg * 8;                                            \
            const unsigned short* p = (k < DIN) ? (Ab + (size_t)ncl * DIN + k)     \
                                                : (Fb + (size_t)ncl * DIN + (k - DIN)); \
            dst[kk] = *reinterpret_cast<const bf16x8*>(p);                         \
        }                                                                          \
    }

    #define COMPUTE(g, ab)                                                         \
    {                                                                              \
        f32x4 acc0 = {0.f, 0.f, 0.f, 0.f}, acc1 = {0.f, 0.f, 0.f, 0.f};           \
        _Pragma("unroll")                                                          \
        for (int kk = 0; kk < KK; ++kk) {                                          \
            acc0 = __builtin_amdgcn_mfma_f32_16x16x32_bf16(ab[kk], b0[kk], acc0, 0, 0, 0); \
            acc1 = __builtin_amdgcn_mfma_f32_16x16x32_bf16(ab[kk], b1[kk], acc1, 0, 0, 0); \
        }                                                                          \
        int gbase = (g0 + (g)) * 16 + kseg * 4;                                    \
        _Pragma("unroll")                                                          \
        for (int r = 0; r < 4; ++r) {                                              \
            int gn = gbase + r;                                                    \
            if (gn < n) {                                                          \
                int col0 = wc * 32 + arow;                                         \
                float v0 = fmaxf(acc0[r] + bv0, 0.f);                              \
                float v1 = fmaxf(acc1[r] + bv1, 0.f);                              \
                out[(size_t)gn * outs + col0] = v0;                                \
                out[(size_t)gn * outs + col0 + 16] = v1;                           \
                if constexpr (WB) {                                                \
                    outb[(size_t)gn * DOUT + col0] = f2bf(v0);                     \
                    outb[(size_t)gn * DOUT + col0 + 16] = f2bf(v1);                \
                }                                                                  \
            }                                                                      \
        }                                                                          \
    }

    LOADA(0, a0);
    #pragma unroll
    for (int gp = 0; gp < GW; gp += 2) {
        LOADA(gp + 1, a1);
        COMPUTE(gp, a0);
        if (gp + 2 < GW) LOADA(gp + 2, a0);
        COMPUTE(gp + 1, a1);
    }
    #undef LOADA
    #undef COMPUTE
}

extern "C" void kernel_launch(void* const* d_in, const int* in_sizes, int n_in,
                              void* d_out, int out_size, void* d_ws, size_t ws_size,
                              hipStream_t stream) {
    const float* x   = (const float*)d_in[0];
    const int*   ei  = (const int*)d_in[1];
    const float* W1l = (const float*)d_in[2];
    const float* b1  = (const float*)d_in[3];
    const float* W1r = (const float*)d_in[4];
    const float* W2l = (const float*)d_in[5];
    const float* b2  = (const float*)d_in[6];
    const float* W2r = (const float*)d_in[7];
    const float* W3l = (const float*)d_in[8];
    const float* b3  = (const float*)d_in[9];
    const float* W3r = (const float*)d_in[10];
    float* out = (float*)d_out;

    const int* src = ei;
    const int* dst = ei + N_EDGES;

    int* wsi = (int*)d_ws;
    int*   cnt      = wsi;                    // NP
    int*   total    = wsi + NP;               // 64
    int*   row_ptr  = wsi + NP + 64;          // NP
    int*   cursor   = wsi + 2 * NP + 64;      // NP
    float* inv_deg  = (float*)(wsi + 3 * NP + 64);   // NP
    int*   edge_src = wsi + 4 * NP + 64;      // E
    unsigned short* Wc2 = (unsigned short*)(edge_src + N_EDGES);  // 64*256
    unsigned short* Wc3 = Wc2 + 64 * 256;                         // 128*128
    unsigned short* meanb = Wc3 + 128 * 128;                      // N*128 bf16
    unsigned short* xlb = meanb + (size_t)N_NODES * 128;          // N*128 bf16 (x@W1l^T)
    unsigned short* s1b = xlb + (size_t)N_NODES * 128;            // N*128 bf16 (x@W1r^T + b1)
    unsigned short* h1b = s1b + (size_t)N_NODES * 128;            // N*128 bf16
    unsigned short* h2b = h1b + (size_t)N_NODES * 128;            // N*64  bf16

    zero_kernel<<<(NP + 64 + 255) / 256, 256, 0, stream>>>(cnt, NP + 64);

    prep_kernel<<<ATB + PGB + WCB2, 256, 0, stream>>>(dst, cnt, x,
        W1l, b1, W1r, W2l, W2r, W3l, W3r, xlb, s1b, Wc2, Wc3);

    assign_kernel<<<NP / 256, 256, 0, stream>>>(cnt, row_ptr, cursor, inv_deg, total, N_NODES);
    fill_kernel<<<ATB, 256, 0, stream>>>(src, dst, cursor, edge_src);

    const int AGG_BLOCKS = (N_NODES + 3) / 4;
    const int GB128 = (N_NODES + 127) / 128;   // 391 (DOUT=64 gemm, R8 config)
    const int GB64  = (N_NODES + 63) / 64;     // 782

    // layer 1: aggregate xlb + merge s1b -> out cols [0,128) + h1b
    agg1_kernel<<<AGG_BLOCKS, 256, 0, stream>>>(xlb, row_ptr, cnt, edge_src,
        inv_deg, s1b, out, h1b, N_NODES);

    // layer 2
    agg_kernel<128><<<AGG_BLOCKS, 256, 0, stream>>>(h1b, row_ptr, cnt, edge_src,
        inv_deg, meanb, N_NODES);
    mfma_gemm_kernel<256, 64, true><<<GB128, 256, 0, stream>>>(meanb, h1b, Wc2, b2,
        out + 128, 320, h2b, N_NODES);

    // layer 3
    agg_kernel<64><<<AGG_BLOCKS, 256, 0, stream>>>(h2b, row_ptr, cnt, edge_src,
        inv_deg, meanb, N_NODES);
    mfma_gemm_kernel<128, 128, false><<<GB64, 256, 0, stream>>>(meanb, h2b, Wc3, b3,
        out + 192, 320, nullptr, N_NODES);
}

// Round 17
// 218.847 us; speedup vs baseline: 1.1335x; 1.1335x over previous
//
#include <hip/hip_runtime.h>
#include <hip/hip_bf16.h>

#define N_NODES 50000
#define N_EDGES 800000

constexpr int NP = 50176;                          // N_NODES padded to 256
constexpr int E4 = N_EDGES / 4;                    // 200000 (fill: 4 edges/thread)
constexpr int E8 = N_EDGES / 8;                    // 100000 (count: 8 edges/thread)
constexpr int ATB = (E8 + 255) / 256;              // 391 atomic blocks
constexpr int PGB = 98 * 32;                       // 3136 pregemm blocks (XCD-swizzled)
constexpr int WCB2 = (64 * 256 + 128 * 128) / 256; // 128 blocks for Wc2+Wc3

typedef __attribute__((ext_vector_type(8))) short bf16x8;
typedef __attribute__((ext_vector_type(4))) float f32x4;

__device__ __forceinline__ unsigned short f2bf(float f) {
    unsigned u = __float_as_uint(f);
    u += 0x7FFFu + ((u >> 16) & 1u);   // round-nearest-even
    return (unsigned short)(u >> 16);
}

__device__ __forceinline__ bf16x8 pack8(float4 f0, float4 f1) {
    bf16x8 r;
    r[0] = (short)f2bf(f0.x); r[1] = (short)f2bf(f0.y);
    r[2] = (short)f2bf(f0.z); r[3] = (short)f2bf(f0.w);
    r[4] = (short)f2bf(f1.x); r[5] = (short)f2bf(f1.y);
    r[6] = (short)f2bf(f1.z); r[7] = (short)f2bf(f1.w);
    return r;
}

// ---------------- zero counters ----------------
__global__ void zero_kernel(int* __restrict__ p, int n) {
    int i = blockIdx.x * 256 + threadIdx.x;
    if (i < n) p[i] = 0;
}

// ---------------- prep: atomic wall + LDS-staged pregemm (XCD-local) + Wc builds ----------------
// Final configuration (R14, best measured 219.9us). Wall model: under-wall
// co-scheduled work is free iff VGPR<=64 (launch_bounds 256,8) and its traffic
// fits the ~1.5TB/s x 40us byte budget; XCD-swizzled mapping keeps x reads L2-local.
__global__ __launch_bounds__(256, 8) void prep_kernel(
        const int* __restrict__ dst, int* __restrict__ cnt, int* __restrict__ pos,
        const float* __restrict__ x,
        const float* __restrict__ W1l, const float* __restrict__ b1,
        const float* __restrict__ W1r,
        const float* __restrict__ W2l, const float* __restrict__ W2r,
        const float* __restrict__ W3l, const float* __restrict__ W3r,
        unsigned short* __restrict__ xlb, unsigned short* __restrict__ s1b,
        unsigned short* __restrict__ Wc2, unsigned short* __restrict__ Wc3) {
    __shared__ unsigned short Asl[64 * 136];   // 64 rows, 272B stride
    int b = blockIdx.x;
    int tid = threadIdx.x;
    if (b < ATB) {
        // ---- atomic wall: 8 edges/thread ----
        int t8 = b * 256 + tid;
        if (t8 < E8) {
            int4 d0 = reinterpret_cast<const int4*>(dst)[t8 * 2];
            int4 d1 = reinterpret_cast<const int4*>(dst)[t8 * 2 + 1];
            int4 p0, p1;
            p0.x = atomicAdd(&cnt[d0.x], 1);
            p0.y = atomicAdd(&cnt[d0.y], 1);
            p0.z = atomicAdd(&cnt[d0.z], 1);
            p0.w = atomicAdd(&cnt[d0.w], 1);
            p1.x = atomicAdd(&cnt[d1.x], 1);
            p1.y = atomicAdd(&cnt[d1.y], 1);
            p1.z = atomicAdd(&cnt[d1.z], 1);
            p1.w = atomicAdd(&cnt[d1.w], 1);
            reinterpret_cast<int4*>(pos)[t8 * 2] = p0;
            reinterpret_cast<int4*>(pos)[t8 * 2 + 1] = p1;
        }
    } else if (b < ATB + PGB) {
        // ---- layer-1 pregemm, XCD-local mapping ----
        int p = b - ATB;
        int ng = (p >> 5) * 8 + (p & 7);
        int cg = (p >> 3) & 3;
        if (ng >= 782) return;
        int nb0 = ng * 64;
        {
            int r = tid >> 2, q = tid & 3;
            int node = nb0 + r;
            int ncl = node < N_NODES ? node : 0;
            const float4* xp = reinterpret_cast<const float4*>(x + (size_t)ncl * 128 + q * 32);
            #pragma unroll
            for (int i = 0; i < 4; ++i) {
                float4 f0 = xp[2 * i];
                float4 f1 = xp[2 * i + 1];
                uint4 w;
                w.x = (unsigned)f2bf(f0.x) | ((unsigned)f2bf(f0.y) << 16);
                w.y = (unsigned)f2bf(f0.z) | ((unsigned)f2bf(f0.w) << 16);
                w.z = (unsigned)f2bf(f1.x) | ((unsigned)f2bf(f1.y) << 16);
                w.w = (unsigned)f2bf(f1.z) | ((unsigned)f2bf(f1.w) << 16);
                *reinterpret_cast<uint4*>(&Asl[r * 136 + q * 32 + i * 8]) = w;
            }
        }
        __syncthreads();
        int wave = tid >> 6, lane = tid & 63;
        int arow = lane & 15, kseg = lane >> 4;
        int col = cg * 64 + wave * 16 + arow;      // 0..255
        const float* wrow = (col < 128) ? (W1l + (size_t)col * 128)
                                        : (W1r + (size_t)(col - 128) * 128);
        bf16x8 bw[4];
        #pragma unroll
        for (int kk = 0; kk < 4; ++kk) {
            float4 f0 = *reinterpret_cast<const float4*>(wrow + kk * 32 + kseg * 8);
            float4 f1 = *reinterpret_cast<const float4*>(wrow + kk * 32 + kseg * 8 + 4);
            bw[kk] = pack8(f0, f1);
        }
        float bias_v = (col < 128) ? 0.f : b1[col - 128];
        unsigned short* outbase = (col < 128) ? xlb : s1b;
        int ocol = (col < 128) ? col : (col - 128);
        #pragma unroll
        for (int g = 0; g < 4; ++g) {
            bf16x8 a[4];
            #pragma unroll
            for (int kk = 0; kk < 4; ++kk)
                a[kk] = *reinterpret_cast<const bf16x8*>(
                    &Asl[(g * 16 + arow) * 136 + kk * 32 + kseg * 8]);
            f32x4 acc = {0.f, 0.f, 0.f, 0.f};
            #pragma unroll
            for (int kk = 0; kk < 4; ++kk)
                acc = __builtin_amdgcn_mfma_f32_16x16x32_bf16(a[kk], bw[kk], acc, 0, 0, 0);
            int gn0 = nb0 + g * 16 + kseg * 4;
            #pragma unroll
            for (int r = 0; r < 4; ++r) {
                int gn = gn0 + r;
                if (gn < N_NODES)
                    outbase[(size_t)gn * 128 + ocol] = f2bf(acc[r] + bias_v);
            }
        }
    } else {
        // ---- Wc2 / Wc3 builds ----
        int idx = (b - ATB - PGB) * 256 + tid;   // [0, 32768)
        if (idx < 16384) {
            int nr = idx >> 8, k = idx & 255;
            float v = (k < 128) ? W2l[nr * 128 + k] : W2r[nr * 128 + (k - 128)];
            Wc2[idx] = f2bf(v);
        } else {
            int j = idx - 16384;
            int nr = j >> 7, k = j & 127;
            float v = (k < 64) ? W3l[nr * 64 + k] : W3r[nr * 64 + (k - 64)];
            Wc3[j] = f2bf(v);
        }
    }
}

__global__ void assign_kernel(const int* __restrict__ cnt, int* __restrict__ row_ptr,
                              float* __restrict__ inv_deg, int* __restrict__ total, int n) {
    int i = blockIdx.x * blockDim.x + threadIdx.x;
    int lane = threadIdx.x & 63;
    int v = (i < n) ? cnt[i] : 0;
    int s = v;
    #pragma unroll
    for (int off = 1; off < 64; off <<= 1) {
        int t = __shfl_up(s, off);
        if (lane >= off) s += t;
    }
    int base = 0;
    if (lane == 63) base = atomicAdd(total, s);
    base = __shfl(base, 63);
    if (i < n) {
        row_ptr[i] = base + s - v;
        inv_deg[i] = 1.0f / (float)(v > 1 ? v : 1);
    }
}

// atomic-free scatter, 4 edges/thread
__global__ void fill_kernel(const int* __restrict__ src, const int* __restrict__ dst,
                            const int* __restrict__ row_ptr,
                            const int* __restrict__ pos, int* __restrict__ edge_src) {
    int t4 = blockIdx.x * 256 + threadIdx.x;
    if (t4 < E4) {
        int4 s4 = reinterpret_cast<const int4*>(src)[t4];
        int4 d4 = reinterpret_cast<const int4*>(dst)[t4];
        int4 p4 = reinterpret_cast<const int4*>(pos)[t4];
        edge_src[row_ptr[d4.x] + p4.x] = s4.x;
        edge_src[row_ptr[d4.y] + p4.y] = s4.y;
        edge_src[row_ptr[d4.z] + p4.z] = s4.z;
        edge_src[row_ptr[d4.w] + p4.w] = s4.w;
    }
}

// ---------------- layer-1: aggregate xlb + merge s1b (relu) ----------------
__global__ __launch_bounds__(256) void agg1_kernel(
        const unsigned short* __restrict__ hb,     // xlb
        const int* __restrict__ row_ptr, const int* __restrict__ cnt,
        const int* __restrict__ edge_src, const float* __restrict__ inv_deg,
        const unsigned short* __restrict__ s1b,
        float* __restrict__ outF, unsigned short* __restrict__ h1b, int n) {
    constexpr int LPR = 16, EPW = 4;
    int wid = (blockIdx.x * 256 + threadIdx.x) >> 6;
    int lane = threadIdx.x & 63;
    if (wid >= n) return;
    int beg = row_ptr[wid];
    int end = beg + cnt[wid];
    float inv = inv_deg[wid];
    int sub = lane / LPR, li = lane % LPR;

    float acc[8];
    #pragma unroll
    for (int j = 0; j < 8; ++j) acc[j] = 0.f;
    for (int e0 = beg; e0 < end; e0 += 4 * EPW) {
        int ea = e0 + sub, eb = ea + EPW, ec = ea + 2 * EPW, ed = ea + 3 * EPW;
        uint4 v0 = {0u,0u,0u,0u}, v1 = {0u,0u,0u,0u}, v2 = {0u,0u,0u,0u}, v3 = {0u,0u,0u,0u};
        if (ea < end) v0 = *reinterpret_cast<const uint4*>(hb + (size_t)edge_src[ea] * 128 + li * 8);
        if (eb < end) v1 = *reinterpret_cast<const uint4*>(hb + (size_t)edge_src[eb] * 128 + li * 8);
        if (ec < end) v2 = *reinterpret_cast<const uint4*>(hb + (size_t)edge_src[ec] * 128 + li * 8);
        if (ed < end) v3 = *reinterpret_cast<const uint4*>(hb + (size_t)edge_src[ed] * 128 + li * 8);
        unsigned w;
        #define ACCW(u, j0) w = (u); acc[j0] += __uint_as_float(w << 16); acc[j0+1] += __uint_as_float(w & 0xFFFF0000u)
        ACCW(v0.x, 0); ACCW(v0.y, 2); ACCW(v0.z, 4); ACCW(v0.w, 6);
        ACCW(v1.x, 0); ACCW(v1.y, 2); ACCW(v1.z, 4); ACCW(v1.w, 6);
        ACCW(v2.x, 0); ACCW(v2.y, 2); ACCW(v2.z, 4); ACCW(v2.w, 6);
        ACCW(v3.x, 0); ACCW(v3.y, 2); ACCW(v3.z, 4); ACCW(v3.w, 6);
        #undef ACCW
    }
    #pragma unroll
    for (int off = LPR; off < 64; off <<= 1) {
        #pragma unroll
        for (int j = 0; j < 8; ++j) acc[j] += __shfl_xor(acc[j], off);
    }
    if (lane < LPR) {
        uint4 s4 = *reinterpret_cast<const uint4*>(s1b + (size_t)wid * 128 + li * 8);
        float v[8];
        v[0] = fmaxf(acc[0] * inv + __uint_as_float(s4.x << 16), 0.f);
        v[1] = fmaxf(acc[1] * inv + __uint_as_float(s4.x & 0xFFFF0000u), 0.f);
        v[2] = fmaxf(acc[2] * inv + __uint_as_float(s4.y << 16), 0.f);
        v[3] = fmaxf(acc[3] * inv + __uint_as_float(s4.y & 0xFFFF0000u), 0.f);
        v[4] = fmaxf(acc[4] * inv + __uint_as_float(s4.z << 16), 0.f);
        v[5] = fmaxf(acc[5] * inv + __uint_as_float(s4.z & 0xFFFF0000u), 0.f);
        v[6] = fmaxf(acc[6] * inv + __uint_as_float(s4.w << 16), 0.f);
        v[7] = fmaxf(acc[7] * inv + __uint_as_float(s4.w & 0xFFFF0000u), 0.f);
        float4 r0 = {v[0], v[1], v[2], v[3]};
        float4 r1 = {v[4], v[5], v[6], v[7]};
        float* op = outF + (size_t)wid * 320 + li * 8;
        *reinterpret_cast<float4*>(op) = r0;
        *reinterpret_cast<float4*>(op + 4) = r1;
        uint4 w;
        w.x = (unsigned)f2bf(v[0]) | ((unsigned)f2bf(v[1]) << 16);
        w.y = (unsigned)f2bf(v[2]) | ((unsigned)f2bf(v[3]) << 16);
        w.z = (unsigned)f2bf(v[4]) | ((unsigned)f2bf(v[5]) << 16);
        w.w = (unsigned)f2bf(v[6]) | ((unsigned)f2bf(v[7]) << 16);
        *reinterpret_cast<uint4*>(h1b + (size_t)wid * 128 + li * 8) = w;
    }
}

// ---------------- mean aggregation (layers 2,3): wave per node, ILP-4 ----------------
template<int D>
__global__ __launch_bounds__(256) void agg_kernel(
        const unsigned short* __restrict__ hb,
        const int* __restrict__ row_ptr, const int* __restrict__ cnt,
        const int* __restrict__ edge_src,
        const float* __restrict__ inv_deg, unsigned short* __restrict__ meanb, int n) {
    constexpr int LPR = D / 8;
    constexpr int EPW = 64 / LPR;
    int wid = (blockIdx.x * 256 + threadIdx.x) >> 6;
    int lane = threadIdx.x & 63;
    if (wid >= n) return;
    int beg = row_ptr[wid];
    int end = beg + cnt[wid];
    float inv = inv_deg[wid];
    int sub = lane / LPR;
    int li = lane % LPR;

    float acc[8];
    #pragma unroll
    for (int j = 0; j < 8; ++j) acc[j] = 0.f;

    for (int e0 = beg; e0 < end; e0 += 4 * EPW) {
        int ea = e0 + sub;
        int eb = ea + EPW;
        int ec = ea + 2 * EPW;
        int ed = ea + 3 * EPW;
        uint4 v0 = {0u,0u,0u,0u}, v1 = {0u,0u,0u,0u}, v2 = {0u,0u,0u,0u}, v3 = {0u,0u,0u,0u};
        if (ea < end) v0 = *reinterpret_cast<const uint4*>(hb + (size_t)edge_src[ea] * D + li * 8);
        if (eb < end) v1 = *reinterpret_cast<const uint4*>(hb + (size_t)edge_src[eb] * D + li * 8);
        if (ec < end) v2 = *reinterpret_cast<const uint4*>(hb + (size_t)edge_src[ec] * D + li * 8);
        if (ed < end) v3 = *reinterpret_cast<const uint4*>(hb + (size_t)edge_src[ed] * D + li * 8);
        unsigned w;
        #define ACCW(u, j0) w = (u); acc[j0] += __uint_as_float(w << 16); acc[j0+1] += __uint_as_float(w & 0xFFFF0000u)
        ACCW(v0.x, 0); ACCW(v0.y, 2); ACCW(v0.z, 4); ACCW(v0.w, 6);
        ACCW(v1.x, 0); ACCW(v1.y, 2); ACCW(v1.z, 4); ACCW(v1.w, 6);
        ACCW(v2.x, 0); ACCW(v2.y, 2); ACCW(v2.z, 4); ACCW(v2.w, 6);
        ACCW(v3.x, 0); ACCW(v3.y, 2); ACCW(v3.z, 4); ACCW(v3.w, 6);
        #undef ACCW
    }
    #pragma unroll
    for (int off = LPR; off < 64; off <<= 1) {
        #pragma unroll
        for (int j = 0; j < 8; ++j) acc[j] += __shfl_xor(acc[j], off);
    }
    if (lane < LPR) {
        uint4 w;
        w.x = (unsigned)f2bf(acc[0] * inv) | ((unsigned)f2bf(acc[1] * inv) << 16);
        w.y = (unsigned)f2bf(acc[2] * inv) | ((unsigned)f2bf(acc[3] * inv) << 16);
        w.z = (unsigned)f2bf(acc[4] * inv) | ((unsigned)f2bf(acc[5] * inv) << 16);
        w.w = (unsigned)f2bf(acc[6] * inv) | ((unsigned)f2bf(acc[7] * inv) << 16);
        *reinterpret_cast<uint4*>(meanb + (size_t)wid * D + li * 8) = w;
    }
}

// ---------------- MFMA GEMM v3 (R8 exact): B-in-registers, M-loop per wave ----------------
template<int K, int DOUT, bool WB>
__global__ __launch_bounds__(256, 3) void mfma_gemm_kernel(
        const unsigned short* __restrict__ Ab,
        const unsigned short* __restrict__ Fb,
        const unsigned short* __restrict__ Wc,
        const float* __restrict__ bias,
        float* __restrict__ out, int outs,
        unsigned short* __restrict__ outb, int n) {
    constexpr int DIN = K / 2;
    constexpr int KK = K / 32;
    constexpr int NWC = DOUT / 32;
    constexpr int NWM = 4 / NWC;
    constexpr int GW = 4;
    constexpr int BM = 16 * GW * NWM;
    int wave = threadIdx.x >> 6;
    int lane = threadIdx.x & 63;
    int wc = wave % NWC;
    int wm = wave / NWC;
    int arow = lane & 15;
    int kseg = lane >> 4;

    bf16x8 b0[KK], b1[KK];
    {
        const unsigned short* wp0 = Wc + (size_t)(wc * 32 + arow) * K + kseg * 8;
        const unsigned short* wp1 = wp0 + (size_t)16 * K;
        #pragma unroll
        for (int kk = 0; kk < KK; ++kk) {
            b0[kk] = *reinterpret_cast<const bf16x8*>(wp0 + kk * 32);
            b1[kk] = *reinterpret_cast<const bf16x8*>(wp1 + kk * 32);
        }
    }
    float bv0 = bias[wc * 32 + arow];
    float bv1 = bias[wc * 32 + 16 + arow];

    int g0 = blockIdx.x * (BM / 16) + wm * GW;

    bf16x8 a0[KK], a1[KK];

    #define LOADA(g, dst)                                                          \
    {                                                                              \
        int node = (g0 + (g)) * 16 + arow;                                         \
        int ncl = node < n ? node : 0;                                             \
        _Pragma("unroll")                                                          \
        for (int kk = 0; kk < KK; ++kk) {                                          \
            int k = kk * 32 + kseg * 8;                                            \
            const unsigned short* p = (k < DIN) ? (Ab + (size_t)ncl * DIN + k)     \
                                                : (Fb + (size_t)ncl * DIN + (k - DIN)); \
            dst[kk] = *reinterpret_cast<const bf16x8*>(p);                         \
        }                                                                          \
    }

    #define COMPUTE(g, ab)                                                         \
    {                                                                              \
        f32x4 acc0 = {0.f, 0.f, 0.f, 0.f}, acc1 = {0.f, 0.f, 0.f, 0.f};           \
        _Pragma("unroll")                                                          \
        for (int kk = 0; kk < KK; ++kk) {                                          \
            acc0 = __builtin_amdgcn_mfma_f32_16x16x32_bf16(ab[kk], b0[kk], acc0, 0, 0, 0); \
            acc1 = __builtin_amdgcn_mfma_f32_16x16x32_bf16(ab[kk], b1[kk], acc1, 0, 0, 0); \
        }                                                                          \
        int gbase = (g0 + (g)) * 16 + kseg * 4;                                    \
        _Pragma("unroll")                                                          \
        for (int r = 0; r < 4; ++r) {                                              \
            int gn = gbase + r;                                                    \
            if (gn < n) {                                                          \
                int col0 = wc * 32 + arow;                                         \
                float v0 = fmaxf(acc0[r] + bv0, 0.f);                              \
                float v1 = fmaxf(acc1[r] + bv1, 0.f);                              \
                out[(size_t)gn * outs + col0] = v0;                                \
                out[(size_t)gn * outs + col0 + 16] = v1;                           \
                if constexpr (WB) {                                                \
                    outb[(size_t)gn * DOUT + col0] = f2bf(v0);                     \
                    outb[(size_t)gn * DOUT + col0 + 16] = f2bf(v1);                \
                }                                                                  \
            }                                                                      \
        }                                                                          \
    }

    LOADA(0, a0);
    #pragma unroll
    for (int gp = 0; gp < GW; gp += 2) {
        LOADA(gp + 1, a1);
        COMPUTE(gp, a0);
        if (gp + 2 < GW) LOADA(gp + 2, a0);
        COMPUTE(gp + 1, a1);
    }
    #undef LOADA
    #undef COMPUTE
}

extern "C" void kernel_launch(void* const* d_in, const int* in_sizes, int n_in,
                              void* d_out, int out_size, void* d_ws, size_t ws_size,
                              hipStream_t stream) {
    const float* x   = (const float*)d_in[0];
    const int*   ei  = (const int*)d_in[1];
    const float* W1l = (const float*)d_in[2];
    const float* b1  = (const float*)d_in[3];
    const float* W1r = (const float*)d_in[4];
    const float* W2l = (const float*)d_in[5];
    const float* b2  = (const float*)d_in[6];
    const float* W2r = (const float*)d_in[7];
    const float* W3l = (const float*)d_in[8];
    const float* b3  = (const float*)d_in[9];
    const float* W3r = (const float*)d_in[10];
    float* out = (float*)d_out;

    const int* src = ei;
    const int* dst = ei + N_EDGES;

    int* wsi = (int*)d_ws;
    int*   cnt      = wsi;                    // NP
    int*   total    = wsi + NP;               // 64
    int*   row_ptr  = wsi + NP + 64;          // NP
    float* inv_deg  = (float*)(wsi + 2 * NP + 64);
    int*   edge_src = wsi + 3 * NP + 64;      // E
    int*   pos      = edge_src + N_EDGES;     // E
    unsigned short* Wc2 = (unsigned short*)(pos + N_EDGES);       // 64*256
    unsigned short* Wc3 = Wc2 + 64 * 256;                         // 128*128
    unsigned short* meanb = Wc3 + 128 * 128;                      // N*128 bf16
    unsigned short* xlb = meanb + (size_t)N_NODES * 128;          // N*128 bf16 (x@W1l^T)
    unsigned short* s1b = xlb + (size_t)N_NODES * 128;            // N*128 bf16 (x@W1r^T + b1)
    unsigned short* h1b = s1b + (size_t)N_NODES * 128;            // N*128 bf16
    unsigned short* h2b = h1b + (size_t)N_NODES * 128;            // N*64  bf16

    zero_kernel<<<(NP + 64 + 255) / 256, 256, 0, stream>>>(cnt, NP + 64);

    prep_kernel<<<ATB + PGB + WCB2, 256, 0, stream>>>(dst, cnt, pos, x,
        W1l, b1, W1r, W2l, W2r, W3l, W3r, xlb, s1b, Wc2, Wc3);

    assign_kernel<<<NP / 256, 256, 0, stream>>>(cnt, row_ptr, inv_deg, total, N_NODES);
    fill_kernel<<<(E4 + 255) / 256, 256, 0, stream>>>(src, dst, row_ptr, pos, edge_src);

    const int AGG_BLOCKS = (N_NODES + 3) / 4;
    const int GB128 = (N_NODES + 127) / 128;   // 391 (DOUT=64 gemm, R8 config)
    const int GB64  = (N_NODES + 63) / 64;     // 782

    // layer 1: aggregate xlb + merge s1b -> out cols [0,128) + h1b
    agg1_kernel<<<AGG_BLOCKS, 256, 0, stream>>>(xlb, row_ptr, cnt, edge_src,
        inv_deg, s1b, out, h1b, N_NODES);

    // layer 2
    agg_kernel<128><<<AGG_BLOCKS, 256, 0, stream>>>(h1b, row_ptr, cnt, edge_src,
        inv_deg, meanb, N_NODES);
    mfma_gemm_kernel<256, 64, true><<<GB128, 256, 0, stream>>>(meanb, h1b, Wc2, b2,
        out + 128, 320, h2b, N_NODES);

    // layer 3
    agg_kernel<64><<<AGG_BLOCKS, 256, 0, stream>>>(h2b, row_ptr, cnt, edge_src,
        inv_deg, meanb, N_NODES);
    mfma_gemm_kernel<128, 128, false><<<GB64, 256, 0, stream>>>(meanb, h2b, Wc3, b3,
        out + 192, 320, nullptr, N_NODES);
}